// Round 1
// baseline (483.591 us; speedup 1.0000x reference)
//
#include <hip/hip_runtime.h>

#define BB 1024
#define TT 512
#define KK 64
#define NEGV -10000.0f

// ---------------------------------------------------------------------------
// gold_kernel: gold_score[b] = sum_t trans[tag_t][tag_{t-1}] + feats[b,t,tag_t]
//              + trans[STOP][tag_{T-1}]   (START=0 prepended, STOP=K-1)
// one wave per batch, 4 waves per block
// ---------------------------------------------------------------------------
__global__ __launch_bounds__(256) void gold_kernel(const float* __restrict__ feats,
                                                   const int* __restrict__ tags,
                                                   const float* __restrict__ trans,
                                                   float* __restrict__ gold) {
    const int wv = threadIdx.x >> 6;
    const int lane = threadIdx.x & 63;
    const int b = blockIdx.x * 4 + wv;
    const int* tg = tags + (size_t)b * TT;
    float acc = 0.f;
#pragma unroll
    for (int i = 0; i < TT / 64; ++i) {
        int t = lane + i * 64;
        int nxt = tg[t];
        int prv = (t == 0) ? 0 : tg[t - 1];
        acc += trans[nxt * KK + prv] + feats[((size_t)b * TT + t) * KK + nxt];
    }
    if (lane == 0) acc += trans[(KK - 1) * KK + tg[TT - 1]];  // STOP term
#pragma unroll
    for (int d = 1; d < 64; d <<= 1) acc += __shfl_xor(acc, d);
    if (lane == 0) gold[b] = acc;
}

// ---------------------------------------------------------------------------
// crf_kernel: one wave (= one block) per batch. lane = state.
// Forward recurrence in exp-domain (FMA w/ precomputed Er=exp(tr)),
// Viterbi exact in fp32 (bitwise identical adds/maxes vs reference),
// backpointers in LDS, in-kernel backtrace.
// ---------------------------------------------------------------------------
__global__ __launch_bounds__(64, 1) void crf_kernel(const float* __restrict__ feats,
                                                    const float* __restrict__ trans,
                                                    const float* __restrict__ gold,
                                                    float* __restrict__ out) {
    __shared__ unsigned char bp[TT][KK];   // 32 KB backpointers
    __shared__ float ea_buf[KK];           // exp(alpha - am) broadcast
    __shared__ float wa_buf[KK];           // viterbi alpha broadcast
    __shared__ unsigned char path_buf[TT];

    const int b = blockIdx.x;
    const int lane = threadIdx.x;

    // per-lane transition row (lane = next): tr[p] = trans[lane][p]
    float tr[KK];
    float Er[KK];
    {
        const float4* trow = reinterpret_cast<const float4*>(trans + lane * KK);
#pragma unroll
        for (int i = 0; i < KK / 4; ++i) {
            float4 v = trow[i];
            tr[4 * i + 0] = v.x; tr[4 * i + 1] = v.y;
            tr[4 * i + 2] = v.z; tr[4 * i + 3] = v.w;
        }
#pragma unroll
        for (int p = 0; p < KK; ++p) Er[p] = __expf(tr[p]);
    }
    const float t63 = trans[(KK - 1) * KK + lane];  // trans[STOP][lane]

    float a = (lane == 0) ? 0.f : NEGV;   // forward alpha (log domain)
    float w = a;                          // viterbi alpha
    wa_buf[lane] = w;

    // initial wave max of a
    float am = a;
#pragma unroll
    for (int d = 32; d; d >>= 1) am = fmaxf(am, __shfl_xor(am, d));

    const float* fb = feats + (size_t)b * TT * KK + lane;
    float f_next = fb[0];

    for (int t = 0; t < TT; ++t) {
        const float f_cur = f_next;
        {
            int tn = (t + 1 < TT) ? (t + 1) : (TT - 1);
            f_next = fb[tn * KK];          // prefetch next step's emission
        }
        // broadcast normalized forward alpha
        float eav = __expf(a - am);
        ea_buf[lane] = eav;
        // (single-wave block: LDS ops execute in order, no barrier needed)

        float fa0 = 0.f, fa1 = 0.f, fa2 = 0.f, fa3 = 0.f;
        float gm[8];
#pragma unroll
        for (int gi = 0; gi < 8; ++gi) gm[gi] = -3.4e38f;

        const float4* eb = reinterpret_cast<const float4*>(ea_buf);
        const float4* wb = reinterpret_cast<const float4*>(wa_buf);
#pragma unroll
        for (int q = 0; q < 16; ++q) {
            float4 e4 = eb[q];
            float4 w4 = wb[q];
            fa0 = fmaf(Er[4 * q + 0], e4.x, fa0);
            fa1 = fmaf(Er[4 * q + 1], e4.y, fa1);
            fa2 = fmaf(Er[4 * q + 2], e4.z, fa2);
            fa3 = fmaf(Er[4 * q + 3], e4.w, fa3);
            float v0 = w4.x + tr[4 * q + 0];
            float v1 = w4.y + tr[4 * q + 1];
            float v2 = w4.z + tr[4 * q + 2];
            float v3 = w4.w + tr[4 * q + 3];
            int g = q >> 1;
            gm[g] = fmaxf(fmaxf(gm[g], v0), v1);
            gm[g] = fmaxf(fmaxf(gm[g], v2), v3);
        }

        // ---- forward update ----
        float s = (fa0 + fa1) + (fa2 + fa3);
        float a_new = __logf(s) + am + f_cur;

        // wave max of new alpha (off critical path: overlaps viterbi epilogue)
        float am_new = a_new;
#pragma unroll
        for (int d = 32; d; d >>= 1) am_new = fmaxf(am_new, __shfl_xor(am_new, d));

        // ---- viterbi epilogue ----
        float m = fmaxf(fmaxf(fmaxf(gm[0], gm[1]), fmaxf(gm[2], gm[3])),
                        fmaxf(fmaxf(gm[4], gm[5]), fmaxf(gm[6], gm[7])));
        int g = 0;
#pragma unroll
        for (int j = 7; j >= 0; --j)          // descending: smallest matching group wins
            if (gm[j] == m) g = j;
        const int base = g * 8;
        // re-fetch the winning group's operands (bitwise-identical values)
        const float4* wam = reinterpret_cast<const float4*>(wa_buf + base);
        float4 wa0 = wam[0], wa1 = wam[1];
        const float4* trg = reinterpret_cast<const float4*>(trans + lane * KK + base);
        float4 tg0 = trg[0], tg1 = trg[1];
        int bpv = base;
        {
            float vv;
            vv = wa1.w + tg1.w; if (vv == m) bpv = base + 7;
            vv = wa1.z + tg1.z; if (vv == m) bpv = base + 6;
            vv = wa1.y + tg1.y; if (vv == m) bpv = base + 5;
            vv = wa1.x + tg1.x; if (vv == m) bpv = base + 4;
            vv = wa0.w + tg0.w; if (vv == m) bpv = base + 3;
            vv = wa0.z + tg0.z; if (vv == m) bpv = base + 2;
            vv = wa0.y + tg0.y; if (vv == m) bpv = base + 1;
            vv = wa0.x + tg0.x; if (vv == m) bpv = base + 0;
        }
        bp[t][lane] = (unsigned char)bpv;
        float w_new = m + f_cur;
        wa_buf[lane] = w_new;   // issued after all reads of wa_buf: in-order LDS pipe
        w = w_new;
        a = a_new;
        am = am_new;
    }

    // ---- forward score: logsumexp(alpha_T + trans[STOP][:]) ----
    float v = a + t63;
    float mm = v;
#pragma unroll
    for (int d = 32; d; d >>= 1) mm = fmaxf(mm, __shfl_xor(mm, d));
    float es = __expf(v - mm);
#pragma unroll
    for (int d = 32; d; d >>= 1) es += __shfl_xor(es, d);
    float fscore = mm + __logf(es);

    // ---- viterbi terminal: max + first-index argmax ----
    float tv = w + t63;
    float bvv = tv;
    int bidx = lane;
#pragma unroll
    for (int d = 1; d < 64; d <<= 1) {
        float ov = __shfl_xor(bvv, d);
        int oi = __shfl_xor(bidx, d);
        bool take = (ov > bvv) || (ov == bvv && oi < bidx);
        bvv = take ? ov : bvv;
        bidx = take ? oi : bidx;
    }

    if (lane == 0) {
        out[b] = fscore - gold[b];
        out[BB + b] = bvv;
        int cur = bidx;
        for (int t = TT - 1; t >= 0; --t) {
            path_buf[t] = (unsigned char)cur;
            cur = bp[t][cur];
        }
    }
    __syncthreads();
#pragma unroll
    for (int i = 0; i < TT / KK; ++i) {
        int t = lane + i * KK;
        out[2 * BB + (size_t)b * TT + t] = (float)path_buf[t];
    }
}

extern "C" void kernel_launch(void* const* d_in, const int* in_sizes, int n_in,
                              void* d_out, int out_size, void* d_ws, size_t ws_size,
                              hipStream_t stream) {
    const float* feats = (const float*)d_in[0];
    const int* tags = (const int*)d_in[1];
    const float* trans = (const float*)d_in[2];
    float* out = (float*)d_out;
    float* gold = (float*)d_ws;

    gold_kernel<<<BB / 4, 256, 0, stream>>>(feats, tags, trans, gold);
    crf_kernel<<<BB, 64, 0, stream>>>(feats, trans, gold, out);
}

// Round 2
// 387.850 us; speedup vs baseline: 1.2469x; 1.2469x over previous
//
#include <hip/hip_runtime.h>

#define BB 1024
#define TT 512
#define KK 64
#define NEGV -10000.0f

typedef _Float16 h2 __attribute__((ext_vector_type(2)));

#if defined(__has_builtin)
#if __has_builtin(__builtin_amdgcn_fdot2)
#define HAVE_FDOT2 1
#endif
#endif

static __device__ __forceinline__ float dot2_acc(h2 a, h2 b, float c) {
#ifdef HAVE_FDOT2
    return __builtin_amdgcn_fdot2(a, b, c, false);
#else
    return fmaf((float)a.x, (float)b.x, fmaf((float)a.y, (float)b.y, c));
#endif
}

static __device__ __forceinline__ h2 bc_h2(float f) {
    return __builtin_bit_cast(h2, f);
}

// ---------------------------------------------------------------------------
// gold_kernel: gold_score[b] = sum_t trans[tag_t][tag_{t-1}] + feats[b,t,tag_t]
//              + trans[STOP][tag_{T-1}]
// ---------------------------------------------------------------------------
__global__ __launch_bounds__(256) void gold_kernel(const float* __restrict__ feats,
                                                   const int* __restrict__ tags,
                                                   const float* __restrict__ trans,
                                                   float* __restrict__ gold) {
    const int wv = threadIdx.x >> 6;
    const int lane = threadIdx.x & 63;
    const int b = blockIdx.x * 4 + wv;
    const int* tg = tags + (size_t)b * TT;
    float acc = 0.f;
#pragma unroll
    for (int i = 0; i < TT / 64; ++i) {
        int t = lane + i * 64;
        int nxt = tg[t];
        int prv = (t == 0) ? 0 : tg[t - 1];
        acc += trans[nxt * KK + prv] + feats[((size_t)b * TT + t) * KK + nxt];
    }
    if (lane == 0) acc += trans[(KK - 1) * KK + tg[TT - 1]];  // STOP term
#pragma unroll
    for (int d = 1; d < 64; d <<= 1) acc += __shfl_xor(acc, d);
    if (lane == 0) gold[b] = acc;
}

// ---------------------------------------------------------------------------
// crf_kernel: one block (128 threads = 2 waves) per batch.
//   role 0 wave: forward logsumexp recurrence (f16 ea broadcast + v_dot2)
//   role 1 wave: Viterbi max-plus (exact fp32), backpointers in LDS, backtrace
// Waves are independent per-step (no barriers in the T loop); each hides the
// other's latency on the shared SIMD.
// ---------------------------------------------------------------------------
__global__ __launch_bounds__(128) void crf_kernel(const float* __restrict__ feats,
                                                  const float* __restrict__ trans,
                                                  const float* __restrict__ gold,
                                                  float* __restrict__ out) {
    __shared__ unsigned char bp[TT][KK];            // 32 KB backpointers (vit wave only)
    __shared__ __align__(16) float wa_buf[KK];      // viterbi alpha broadcast
    __shared__ __align__(16) _Float16 ea_buf[KK];   // exp(alpha - ref) broadcast, f16
    __shared__ unsigned char path_buf[TT];
    __shared__ float sh_fscore;
    __shared__ float sh_bvv;

    const int b = blockIdx.x;
    const int wv = threadIdx.x >> 6;
    const int lane = threadIdx.x & 63;
    const int role = wv ^ (b & 1);   // randomize role->SIMD mapping across blocks

    const float* fb = feats + (size_t)b * TT * KK + lane;

    if (role == 0) {
        // ================= FORWARD WAVE =================
        // Er packed as f16 pairs: Er_pk[i] = (exp(tr[2i]), exp(tr[2i+1]))
        h2 Er_pk[32];
        {
            const float4* trow = reinterpret_cast<const float4*>(trans + lane * KK);
#pragma unroll
            for (int i = 0; i < 16; ++i) {
                float4 v = trow[i];
                h2 lo, hi;
                lo.x = (_Float16)__expf(v.x); lo.y = (_Float16)__expf(v.y);
                hi.x = (_Float16)__expf(v.z); hi.y = (_Float16)__expf(v.w);
                Er_pk[2 * i] = lo;
                Er_pk[2 * i + 1] = hi;
            }
        }
        const float t63 = trans[(KK - 1) * KK + lane];  // trans[STOP][lane]

        float a = (lane == 0) ? 0.f : NEGV;
        float ref = 0.f;                       // wave-uniform normalizer
        float f_next = fb[0];

        for (int t = 0; t < TT; ++t) {
            const float f_cur = f_next;
            {
                int tn = (t + 1 < TT) ? (t + 1) : (TT - 1);
                f_next = fb[(size_t)tn * KK];
            }
            // normalized exp, clamped so f16 can never overflow (e^11 < 65504)
            float x = fminf(a - ref, 11.0f);
            ea_buf[lane] = (_Float16)__expf(x);
            // same-wave LDS ops are in order: no barrier needed

            float s0 = 0.f, s1 = 0.f, s2 = 0.f, s3 = 0.f;
            const float4* eb = reinterpret_cast<const float4*>(ea_buf);
#pragma unroll
            for (int q = 0; q < 8; ++q) {
                float4 e4 = eb[q];
                s0 = dot2_acc(bc_h2(e4.x), Er_pk[4 * q + 0], s0);
                s1 = dot2_acc(bc_h2(e4.y), Er_pk[4 * q + 1], s1);
                s2 = dot2_acc(bc_h2(e4.z), Er_pk[4 * q + 2], s2);
                s3 = dot2_acc(bc_h2(e4.w), Er_pk[4 * q + 3], s3);
            }
            float s = (s0 + s1) + (s2 + s3);
            float a_new = __logf(s) + ref + f_cur;
            // cheap near-max reference for next step (single cross-lane op);
            // +3 covers typical deficit of one sample vs the max of 64
            ref = __shfl(a_new, 8) + 3.0f;
            a = a_new;
        }

        // exact terminal logsumexp(alpha_T + trans[STOP][:])
        float v = a + t63;
        float mm = v;
#pragma unroll
        for (int d = 32; d; d >>= 1) mm = fmaxf(mm, __shfl_xor(mm, d));
        float es = __expf(v - mm);
#pragma unroll
        for (int d = 32; d; d >>= 1) es += __shfl_xor(es, d);
        float fscore = mm + __logf(es);
        if (lane == 0) sh_fscore = fscore;
    } else {
        // ================= VITERBI WAVE =================
        float tr[KK];
        {
            const float4* trow = reinterpret_cast<const float4*>(trans + lane * KK);
#pragma unroll
            for (int i = 0; i < KK / 4; ++i) {
                float4 v = trow[i];
                tr[4 * i + 0] = v.x; tr[4 * i + 1] = v.y;
                tr[4 * i + 2] = v.z; tr[4 * i + 3] = v.w;
            }
        }
        const float t63 = trans[(KK - 1) * KK + lane];

        float w = (lane == 0) ? 0.f : NEGV;
        wa_buf[lane] = w;
        float f_next = fb[0];

        for (int t = 0; t < TT; ++t) {
            const float f_cur = f_next;
            {
                int tn = (t + 1 < TT) ? (t + 1) : (TT - 1);
                f_next = fb[(size_t)tn * KK];
            }

            float gm[8];
#pragma unroll
            for (int gi = 0; gi < 8; ++gi) gm[gi] = -3.4e38f;

            const float4* wb = reinterpret_cast<const float4*>(wa_buf);
#pragma unroll
            for (int q = 0; q < 16; ++q) {
                float4 w4 = wb[q];
                float v0 = w4.x + tr[4 * q + 0];
                float v1 = w4.y + tr[4 * q + 1];
                float v2 = w4.z + tr[4 * q + 2];
                float v3 = w4.w + tr[4 * q + 3];
                int g = q >> 1;
                gm[g] = fmaxf(fmaxf(gm[g], v0), v1);   // fuses to v_max3
                gm[g] = fmaxf(fmaxf(gm[g], v2), v3);
            }

            float m = fmaxf(fmaxf(fmaxf(gm[0], gm[1]), fmaxf(gm[2], gm[3])),
                            fmaxf(fmaxf(gm[4], gm[5]), fmaxf(gm[6], gm[7])));
            int g = 0;
#pragma unroll
            for (int j = 7; j >= 0; --j)   // descending: smallest matching group wins
                if (gm[j] == m) g = j;
            const int base = g * 8;
            // re-fetch winning group operands (bitwise-identical adds)
            const float4* wam = reinterpret_cast<const float4*>(wa_buf + base);
            float4 wa0 = wam[0], wa1 = wam[1];
            const float4* trg = reinterpret_cast<const float4*>(trans + lane * KK + base);
            float4 tg0 = trg[0], tg1 = trg[1];
            int bpv = base;
            {
                float vv;
                vv = wa1.w + tg1.w; if (vv == m) bpv = base + 7;
                vv = wa1.z + tg1.z; if (vv == m) bpv = base + 6;
                vv = wa1.y + tg1.y; if (vv == m) bpv = base + 5;
                vv = wa1.x + tg1.x; if (vv == m) bpv = base + 4;
                vv = wa0.w + tg0.w; if (vv == m) bpv = base + 3;
                vv = wa0.z + tg0.z; if (vv == m) bpv = base + 2;
                vv = wa0.y + tg0.y; if (vv == m) bpv = base + 1;
                vv = wa0.x + tg0.x; if (vv == m) bpv = base + 0;
            }
            bp[t][lane] = (unsigned char)bpv;
            float w_new = m + f_cur;
            wa_buf[lane] = w_new;   // after all reads of wa_buf (in-order DS pipe)
            w = w_new;
        }

        // terminal: max + first-index argmax (exact)
        float tv = w + t63;
        float bvv = tv;
        int bidx = lane;
#pragma unroll
        for (int d = 1; d < 64; d <<= 1) {
            float ov = __shfl_xor(bvv, d);
            int oi = __shfl_xor(bidx, d);
            bool take = (ov > bvv) || (ov == bvv && oi < bidx);
            bvv = take ? ov : bvv;
            bidx = take ? oi : bidx;
        }

        if (lane == 0) {
            sh_bvv = bvv;
            int cur = bidx;
            for (int t = TT - 1; t >= 0; --t) {
                path_buf[t] = (unsigned char)cur;
                cur = bp[t][cur];
            }
        }
    }

    __syncthreads();

    if (threadIdx.x == 0) {
        out[b] = sh_fscore - gold[b];
        out[BB + b] = sh_bvv;
    }
#pragma unroll
    for (int i = 0; i < TT / 128; ++i) {
        int t = threadIdx.x + i * 128;
        out[2 * BB + (size_t)b * TT + t] = (float)path_buf[t];
    }
}

extern "C" void kernel_launch(void* const* d_in, const int* in_sizes, int n_in,
                              void* d_out, int out_size, void* d_ws, size_t ws_size,
                              hipStream_t stream) {
    const float* feats = (const float*)d_in[0];
    const int* tags = (const int*)d_in[1];
    const float* trans = (const float*)d_in[2];
    float* out = (float*)d_out;
    float* gold = (float*)d_ws;

    gold_kernel<<<BB / 4, 256, 0, stream>>>(feats, tags, trans, gold);
    crf_kernel<<<BB, 128, 0, stream>>>(feats, trans, gold, out);
}